// Round 8
// baseline (4291.148 us; speedup 1.0000x reference)
//
#include <hip/hip_runtime.h>
#include <hip/hip_bf16.h>

#define DEV __device__ __forceinline__

constexpr int B_ = 256;   // batch
constexpr int T_ = 512;   // time
constexpr int H_ = 128;   // GRU units
constexpr int K_ = 256;   // input dim per layer (D = 2H = 256 for all layers)
constexpr int G_ = 384;   // 3H
constexpr int M_ = B_ * T_;
constexpr int LDSROW = 72;  // ushorts per LDS tile row (64 data + 8 pad)

using bf16 = __hip_bfloat16;
typedef short bf16x8 __attribute__((ext_vector_type(8)));
typedef float f32x4 __attribute__((ext_vector_type(4)));

DEV float tof(float x) { return x; }
DEV float tof(bf16 x) { return __bfloat162float(x); }
DEV void stor(float* p, float v) { *p = v; }
DEV void stor(bf16* p, float v) { *p = __float2bfloat16(v); }

// float -> bf16 bits, round-to-nearest-even
DEV unsigned short f2bs(float f) {
  union { float f; unsigned u; } v;
  v.f = f;
  unsigned r = (v.u + 0x7FFFu + ((v.u >> 16) & 1u)) >> 16;
  return (unsigned short)r;
}
DEV float bs2f(unsigned short s) {
  union { unsigned u; float f; } v;
  v.u = ((unsigned)s) << 16;
  return v.f;
}

DEV float fsigmoid(float x) { return 1.f / (1.f + __expf(-x)); }
DEV float ftanh(float x) {
  x = fminf(20.f, fmaxf(-20.f, x));
  float e = __expf(-2.f * x);
  return (1.f - e) / (1.f + e);
}

// Barrier draining only LDS traffic (lgkmcnt), not global loads/stores.
DEV void barrier_lds() {
  asm volatile("s_waitcnt lgkmcnt(0)\n\ts_barrier" ::: "memory");
}

// MFMA via inline asm with explicit register-file placement:
//   A from VGPRs ("v"), B and C/D in AGPRs ("a").
// B-fragments live in AGPRs and the matrix pipe reads them IN PLACE —
// no v_accvgpr_read shuffling (R3's failure mode).
DEV f32x4 mfma_i(bf16x8 a, bf16x8 b, f32x4 z) {
  f32x4 d;
  asm("v_mfma_f32_16x16x32_bf16 %0, %1, %2, %3"
      : "=a"(d) : "v"(a), "a"(b), "a"(z));
  return d;
}
DEV void mfma_a(f32x4& d, bf16x8 a, bf16x8 b) {
  asm("v_mfma_f32_16x16x32_bf16 %0, %1, %2, %0"
      : "+a"(d) : "v"(a), "a"(b));
}
// Hazard fence: MFMA (4-pass XDL) -> VALU read of D needs ~11 wait states.
// The hazard recognizer cannot see into inline asm, so insert them manually.
DEV void accfence(f32x4& x0, f32x4& x1, f32x4& x2,
                  f32x4& x3, f32x4& x4, f32x4& x5) {
  asm("s_nop 7\n\ts_nop 3"
      : "+a"(x0), "+a"(x1), "+a"(x2), "+a"(x3), "+a"(x4), "+a"(x5));
}

// ---------------------------------------------------------------------------
// convX: split fp32 x[M,256] into bf16 hi/lo arrays (layer-0 GEMM input).
// ---------------------------------------------------------------------------
__global__ __launch_bounds__(256) void convX_kernel(
    const float* __restrict__ x, ushort* __restrict__ hiA,
    ushort* __restrict__ loA) {
  const int n4 = M_ * K_ / 4;
  for (int idx = blockIdx.x * blockDim.x + threadIdx.x; idx < n4;
       idx += gridDim.x * blockDim.x) {
    float4 v = ((const float4*)x)[idx];
    ushort4 h, l;
    h.x = f2bs(v.x); l.x = f2bs(v.x - bs2f(h.x));
    h.y = f2bs(v.y); l.y = f2bs(v.y - bs2f(h.y));
    h.z = f2bs(v.z); l.z = f2bs(v.z - bs2f(h.z));
    h.w = f2bs(v.w); l.w = f2bs(v.w - bs2f(h.w));
    ((ushort4*)hiA)[idx] = h;
    ((ushort4*)loA)[idx] = l;
  }
}

// ---------------------------------------------------------------------------
// convW: W[dir][256][384] fp32 -> W^T hi/lo bf16 [768 ncol][256 k].
// ---------------------------------------------------------------------------
__global__ __launch_bounds__(256) void convW_kernel(
    const float* __restrict__ W, ushort* __restrict__ WhiT,
    ushort* __restrict__ WloT) {
  const int ncol = blockIdx.x;           // 0..767
  const int dir = ncol / G_, j = ncol % G_;
  const int k = threadIdx.x;             // 0..255
  const float f = W[((size_t)dir * K_ + k) * G_ + j];
  const unsigned short hi = f2bs(f);
  WhiT[(size_t)ncol * K_ + k] = hi;
  WloT[(size_t)ncol * K_ + k] = f2bs(f - bs2f(hi));
}

// ---------------------------------------------------------------------------
// gemm3: C[M,768] = A[M,256] @ W^T' + bias, bf16 hi/lo 3-term split MFMA.
// ---------------------------------------------------------------------------
template <typename XT>
__global__ __launch_bounds__(256, 2) void gemm3_kernel(
    const ushort* __restrict__ Ahi, const ushort* __restrict__ Alo,
    const ushort* __restrict__ WhiT, const ushort* __restrict__ WloT,
    const float* __restrict__ bbias, XT* __restrict__ xp) {
  const int m0 = blockIdx.x * 128;
  const int n0 = blockIdx.y * 128;
  const int tid = threadIdx.x;
  const int w = tid >> 6, lane = tid & 63;
  const int wm = w >> 1, wn = w & 1;
  const int col = lane & 15, quad = lane >> 4;

  __shared__ __align__(16) ushort AH[128 * LDSROW];
  __shared__ __align__(16) ushort AL[128 * LDSROW];
  __shared__ __align__(16) ushort BH[128 * LDSROW];
  __shared__ __align__(16) ushort BL[128 * LDSROW];

  f32x4 acc[4][4];
#pragma unroll
  for (int i = 0; i < 4; ++i)
#pragma unroll
    for (int n = 0; n < 4; ++n) acc[i][n] = (f32x4){0.f, 0.f, 0.f, 0.f};

  const ushort* gsrc = (w == 0) ? Ahi : (w == 1) ? Alo : (w == 2) ? WhiT : WloT;
  ushort* lds = (w == 0) ? AH : (w == 1) ? AL : (w == 2) ? BH : BL;
  const int rbase = (w < 2) ? m0 : n0;

  for (int kb = 0; kb < K_; kb += 64) {
#pragma unroll
    for (int q = 0; q < 16; ++q) {
      const int slot = q * 64 + lane;
      const int r = slot >> 3, s = slot & 7;
      bf16x8 v = *(const bf16x8*)(gsrc + (size_t)(rbase + r) * K_ + kb + s * 8);
      *(bf16x8*)&lds[r * LDSROW + s * 8] = v;
    }
    __syncthreads();
#pragma unroll
    for (int z = 0; z < 2; ++z) {
      const int cc8 = (z * 4 + quad) * 8;
      bf16x8 ah[4], al[4], bh[4], bl[4];
#pragma unroll
      for (int i = 0; i < 4; ++i) {
        const int row = wm * 64 + i * 16 + col;
        ah[i] = *(const bf16x8*)&AH[row * LDSROW + cc8];
        al[i] = *(const bf16x8*)&AL[row * LDSROW + cc8];
      }
#pragma unroll
      for (int n = 0; n < 4; ++n) {
        const int row = wn * 64 + n * 16 + col;
        bh[n] = *(const bf16x8*)&BH[row * LDSROW + cc8];
        bl[n] = *(const bf16x8*)&BL[row * LDSROW + cc8];
      }
#pragma unroll
      for (int i = 0; i < 4; ++i)
#pragma unroll
        for (int n = 0; n < 4; ++n) {
          acc[i][n] = __builtin_amdgcn_mfma_f32_16x16x32_bf16(
              ah[i], bh[n], acc[i][n], 0, 0, 0);
          acc[i][n] = __builtin_amdgcn_mfma_f32_16x16x32_bf16(
              al[i], bh[n], acc[i][n], 0, 0, 0);
          acc[i][n] = __builtin_amdgcn_mfma_f32_16x16x32_bf16(
              ah[i], bl[n], acc[i][n], 0, 0, 0);
        }
    }
    __syncthreads();
  }

  const int dir = (n0 >= G_) ? 1 : 0;
#pragma unroll
  for (int n = 0; n < 4; ++n) {
    const int ncol = n0 + wn * 64 + n * 16 + col;
    const int g = ncol - dir * G_;
    const float bv = bbias[dir * 2 * G_ + g];
#pragma unroll
    for (int i = 0; i < 4; ++i) {
      const int mb = m0 + wm * 64 + i * 16 + quad * 4;
#pragma unroll
      for (int r = 0; r < 4; ++r) {
        const int m = mb + r;
        const int bb = m >> 9;          // T_ = 512
        const int t = m & (T_ - 1);
        stor(xp + ((size_t)(dir * T_ + t) * B_ + bb) * G_ + g,
             acc[i][n][r] + bv);
      }
    }
  }
}

// ---------------------------------------------------------------------------
// MFMA recurrence v2. Grid (B/16, 2): 16 batch rows/block, blockIdx.y = dir.
// 512 threads = 8 waves. Wave w owns gate columns z,r,h for units
// [16w,16w+16) -> gate math fully in C/D layout (m=quad*4+r, u=16w+col).
// U hi/lo B-fragments: AGPR-resident (inline-asm "a" constraints), read in
// place by the matrix pipe. h state fp32 in VGPRs; staged to LDS per step as
// RNE-split bf16 hi+lo for the A operand (RNE split everywhere — R7's
// truncation split quadrupled absmax and failed the threshold).
// 3-term MFMA (hi*hi + lo*hi + hi*lo) ~= fp32. Indexing identical to R3.
// ---------------------------------------------------------------------------
template <typename XT, bool LAST>
__global__ __launch_bounds__(512, 2) void rec_mfma2_kernel(
    const XT* __restrict__ xp, const float* __restrict__ Ubase,
    const float* __restrict__ bbase, ushort* __restrict__ seqH,
    ushort* __restrict__ seqL, float* __restrict__ fin) {
  const int dir = blockIdx.y;
  const float* U = Ubase + dir * (H_ * G_);
  const float* bh = bbase + dir * (2 * G_) + G_;
  const int b0 = blockIdx.x * 16;
  const int tid = threadIdx.x;
  const int w = tid >> 6;
  const int lane = tid & 63;
  const int col = lane & 15;
  const int quad = lane >> 4;

  // h staging: bf16 hi/lo, double buffered. Row stride 136 shorts.
  __shared__ __align__(16) short hbH[2][16 * 136];
  __shared__ __align__(16) short hbL[2][16 * 136];

  // B fragments (U columns for this wave's tiles), RNE hi/lo split.
  bf16x8 Bhi[3][4], Blo[3][4];
  const int u = w * 16 + col;
#pragma unroll
  for (int t3 = 0; t3 < 3; ++t3) {
    const int n = t3 * H_ + u;
#pragma unroll
    for (int kb = 0; kb < 4; ++kb) {
#pragma unroll
      for (int jj = 0; jj < 8; ++jj) {
        const int k = kb * 32 + quad * 8 + jj;
        const float f = U[k * G_ + n];
        const unsigned short hi = f2bs(f);
        Bhi[t3][kb][jj] = (short)hi;
        Blo[t3][kb][jj] = (short)f2bs(f - bs2f(hi));
      }
    }
  }
  const float bhz = bh[u], bhr = bh[H_ + u], bhh = bh[2 * H_ + u];

  // zero staging buffer 0 (h0 = 0)
  for (int i = tid; i < 16 * 136; i += 512) { hbH[0][i] = 0; hbL[0][i] = 0; }

  // opaque AGPR zero quad for the chain-initial MFMA C operand
  f32x4 zq = (f32x4){0.f, 0.f, 0.f, 0.f};
  asm("" : "+a"(zq));

  float hst[4] = {0.f, 0.f, 0.f, 0.f};

  const XT* xb = xp + (size_t)(dir * T_) * B_ * G_;

  // prefetch xp for step 0 (gate rows m = quad*4 + r)
  float pz[4], pr[4], ph[4];
  {
    const int t0 = dir ? (T_ - 1) : 0;
#pragma unroll
    for (int r = 0; r < 4; ++r) {
      const XT* row = xb + ((size_t)t0 * B_ + b0 + quad * 4 + r) * G_;
      pz[r] = tof(row[u]); pr[r] = tof(row[H_ + u]); ph[r] = tof(row[2 * H_ + u]);
    }
  }
  barrier_lds();

  const int aoff = col * 136 + quad * 8;  // A-frag: m = lane&15, k = quad*8+j

  for (int it = 0; it < T_; ++it) {
    const int t = dir ? (T_ - 1 - it) : it;
    const int cur = it & 1, nxt = cur ^ 1;

    // prefetch xp for step it+1 (latency hides under MFMA phase)
    float qz[4], qr[4], qh[4];
#pragma unroll
    for (int r = 0; r < 4; ++r) { qz[r] = pz[r]; qr[r] = pr[r]; qh[r] = ph[r]; }
    if (it + 1 < T_) {
      const int tnx = dir ? (t - 1) : (t + 1);
#pragma unroll
      for (int r = 0; r < 4; ++r) {
        const XT* row = xb + ((size_t)tnx * B_ + b0 + quad * 4 + r) * G_;
        qz[r] = tof(row[u]); qr[r] = tof(row[H_ + u]);
        qh[r] = tof(row[2 * H_ + u]);
      }
    }

    // A fragments from LDS
    bf16x8 ahi[4], alo[4];
#pragma unroll
    for (int kb = 0; kb < 4; ++kb) {
      ahi[kb] = *(const bf16x8*)&hbH[cur][aoff + kb * 32];
      alo[kb] = *(const bf16x8*)&hbL[cur][aoff + kb * 32];
    }

    // MFMA: c1 = hi*hi, c2 = lo*hi + hi*lo. All B/C/D in AGPRs via asm.
    f32x4 c10 = mfma_i(ahi[0], Bhi[0][0], zq);
    f32x4 c11 = mfma_i(ahi[0], Bhi[1][0], zq);
    f32x4 c12 = mfma_i(ahi[0], Bhi[2][0], zq);
    f32x4 c20 = mfma_i(alo[0], Bhi[0][0], zq);
    f32x4 c21 = mfma_i(alo[0], Bhi[1][0], zq);
    f32x4 c22 = mfma_i(alo[0], Bhi[2][0], zq);
    mfma_a(c20, ahi[0], Blo[0][0]);
    mfma_a(c21, ahi[0], Blo[1][0]);
    mfma_a(c22, ahi[0], Blo[2][0]);
#pragma unroll
    for (int kb = 1; kb < 4; ++kb) {
      mfma_a(c10, ahi[kb], Bhi[0][kb]);
      mfma_a(c11, ahi[kb], Bhi[1][kb]);
      mfma_a(c12, ahi[kb], Bhi[2][kb]);
      mfma_a(c20, alo[kb], Bhi[0][kb]);
      mfma_a(c21, alo[kb], Bhi[1][kb]);
      mfma_a(c22, alo[kb], Bhi[2][kb]);
      mfma_a(c20, ahi[kb], Blo[0][kb]);
      mfma_a(c21, ahi[kb], Blo[1][kb]);
      mfma_a(c22, ahi[kb], Blo[2][kb]);
    }
    accfence(c10, c11, c12, c20, c21, c22);

    // gate phase, in C/D layout (m = quad*4 + r)
#pragma unroll
    for (int r = 0; r < 4; ++r) {
      const int m = quad * 4 + r;
      const float rz = c10[r] + c20[r] + bhz;
      const float rr = c11[r] + c21[r] + bhr;
      const float rh = c12[r] + c22[r] + bhh;
      const float z = fsigmoid(pz[r] + rz);
      const float rg = fsigmoid(pr[r] + rr);
      const float hh = ftanh(fmaf(rg, rh, ph[r]));
      const float hn = hh + z * (hst[r] - hh);
      hst[r] = hn;
      // RNE hi/lo split
      const unsigned short hi16 = f2bs(hn);
      const unsigned short lo16 = f2bs(hn - bs2f(hi16));
      hbH[nxt][m * 136 + u] = (short)hi16;
      hbL[nxt][m * 136 + u] = (short)lo16;
      if constexpr (!LAST) {
        const size_t sidx =
            ((size_t)(b0 + m) * T_ + t) * (2 * H_) + dir * H_ + u;
        seqH[sidx] = hi16;
        seqL[sidx] = lo16;
      }
    }
#pragma unroll
    for (int r = 0; r < 4; ++r) { pz[r] = qz[r]; pr[r] = qr[r]; ph[r] = qh[r]; }
    barrier_lds();
  }

  if constexpr (LAST) {
#pragma unroll
    for (int r = 0; r < 4; ++r)
      fin[(size_t)(b0 + quad * 4 + r) * (2 * H_) + dir * H_ + u] = hst[r];
  }
}

// ---------------------------------------------------------------------------
// Dense head: out[b] = sigmoid(fin[b][:] . Wd + bd)
// ---------------------------------------------------------------------------
__global__ void dense_kernel(const float* __restrict__ fin,
                             const float* __restrict__ Wd,
                             const float* __restrict__ bd,
                             float* __restrict__ out) {
  __shared__ float w[2 * H_];
  const int tid = threadIdx.x;
  w[tid] = Wd[tid];
  __syncthreads();
  float s = bd[0];
  const float* row = fin + tid * (2 * H_);
#pragma unroll 8
  for (int jj = 0; jj < 2 * H_; ++jj) s = fmaf(row[jj], w[jj], s);
  out[tid] = 1.f / (1.f + __expf(-s));
}

// ---------------------------------------------------------------------------
template <typename XT>
static void run_model(const float* x, const float* Ws, const float* Us,
                      const float* bs, const float* Wd, const float* bd,
                      float* out, char* ws, hipStream_t stream) {
  const size_t xpB = (size_t)2 * T_ * B_ * G_ * sizeof(XT);
  const size_t seqB = (size_t)B_ * T_ * 2 * H_ * 2;  // bf16 bits
  XT* xp = (XT*)ws;
  ushort* sHA = (ushort*)(ws + xpB);
  ushort* sLA = (ushort*)(ws + xpB + seqB);
  ushort* sHB = (ushort*)(ws + xpB + 2 * seqB);
  ushort* sLB = (ushort*)(ws + xpB + 3 * seqB);
  ushort* WhiT = (ushort*)(ws + xpB + 4 * seqB);
  ushort* WloT = WhiT + (size_t)768 * K_;
  float* fin = (float*)(ws + xpB + 4 * seqB + (size_t)2 * 768 * K_ * 2);

  convX_kernel<<<4096, 256, 0, stream>>>(x, sHB, sLB);

  const ushort* AHs[3] = {sHB, sHA, sHB};
  const ushort* ALs[3] = {sLB, sLA, sLB};
  ushort* oH[3] = {sHA, sHB, nullptr};
  ushort* oL[3] = {sLA, sLB, nullptr};

  for (int l = 0; l < 3; ++l) {
    const float* Wl = Ws + (size_t)l * 2 * K_ * G_;
    const float* bl = bs + (size_t)l * 4 * G_;
    const float* Ul = Us + (size_t)l * 2 * H_ * G_;
    convW_kernel<<<768, 256, 0, stream>>>(Wl, WhiT, WloT);
    gemm3_kernel<XT><<<dim3(M_ / 128, 6), 256, 0, stream>>>(
        AHs[l], ALs[l], WhiT, WloT, bl, xp);
    if (l < 2)
      rec_mfma2_kernel<XT, false><<<dim3(B_ / 16, 2), 512, 0, stream>>>(
          xp, Ul, bl, oH[l], oL[l], nullptr);
    else
      rec_mfma2_kernel<XT, true><<<dim3(B_ / 16, 2), 512, 0, stream>>>(
          xp, Ul, bl, nullptr, nullptr, fin);
  }
  dense_kernel<<<1, B_, 0, stream>>>(fin, Wd, bd, out);
}

extern "C" void kernel_launch(void* const* d_in, const int* in_sizes, int n_in,
                              void* d_out, int out_size, void* d_ws,
                              size_t ws_size, hipStream_t stream) {
  const float* x = (const float*)d_in[0];
  const float* Ws = (const float*)d_in[1];
  const float* Us = (const float*)d_in[2];
  const float* bs = (const float*)d_in[3];
  const float* Wd = (const float*)d_in[4];
  const float* bd = (const float*)d_in[5];
  float* out = (float*)d_out;
  char* ws = (char*)d_ws;

  const size_t seqB = (size_t)B_ * T_ * 2 * H_ * 2;
  const size_t wtB = (size_t)2 * 768 * K_ * 2;
  const size_t finB = (size_t)B_ * 2 * H_ * 4;
  const size_t xp32 = (size_t)2 * T_ * B_ * G_ * 4;
  const size_t tierA = xp32 + 4 * seqB + wtB + finB;      // ~641 MiB, fp32 xp
  if (ws_size >= tierA)
    run_model<float>(x, Ws, Us, bs, Wd, bd, out, ws, stream);
  else
    run_model<bf16>(x, Ws, Us, bs, Wd, bd, out, ws, stream);
}

// Round 9
// 2387.763 us; speedup vs baseline: 1.7971x; 1.7971x over previous
//
#include <hip/hip_runtime.h>
#include <hip/hip_bf16.h>

#define DEV __device__ __forceinline__

constexpr int B_ = 256;   // batch
constexpr int T_ = 512;   // time
constexpr int H_ = 128;   // GRU units
constexpr int K_ = 256;   // input dim per layer (D = 2H = 256 for all layers)
constexpr int G_ = 384;   // 3H
constexpr int M_ = B_ * T_;
constexpr int LDSROW = 72;  // ushorts per LDS tile row (64 data + 8 pad)

using bf16 = __hip_bfloat16;
typedef short bf16x8 __attribute__((ext_vector_type(8)));
typedef float f32x4 __attribute__((ext_vector_type(4)));
typedef float f32x2 __attribute__((ext_vector_type(2)));

DEV float tof(float x) { return x; }
DEV float tof(bf16 x) { return __bfloat162float(x); }
DEV void stor(float* p, float v) { *p = v; }
DEV void stor(bf16* p, float v) { *p = __float2bfloat16(v); }

// float -> bf16 bits, round-to-nearest-even
DEV unsigned short f2bs(float f) {
  union { float f; unsigned u; } v;
  v.f = f;
  unsigned r = (v.u + 0x7FFFu + ((v.u >> 16) & 1u)) >> 16;
  return (unsigned short)r;
}
DEV float bs2f(unsigned short s) {
  union { unsigned u; float f; } v;
  v.u = ((unsigned)s) << 16;
  return v.f;
}

DEV float fsigmoid(float x) { return 1.f / (1.f + __expf(-x)); }
DEV float ftanh(float x) {
  x = fminf(20.f, fmaxf(-20.f, x));
  float e = __expf(-2.f * x);
  return (1.f - e) / (1.f + e);
}

// Barrier draining only LDS traffic (lgkmcnt), not global loads/stores.
DEV void barrier_lds() {
  asm volatile("s_waitcnt lgkmcnt(0)\n\ts_barrier" ::: "memory");
}

DEV f32x4 mfma16(bf16x8 a, bf16x8 b, f32x4 c) {
  return __builtin_amdgcn_mfma_f32_16x16x32_bf16(a, b, c, 0, 0, 0);
}

// Butterfly sum over 8-lane groups on the VALU pipe (DPP): masks {1,2,7} =
// quad_perm[1,0,3,2]=0xB1, quad_perm[2,3,0,1]=0x4E, row_half_mirror=0x141.
DEV float dpp_red8(float x) {
  int t;
  t = __builtin_amdgcn_update_dpp(0, __float_as_int(x), 0xB1, 0xF, 0xF, true);
  x += __int_as_float(t);
  t = __builtin_amdgcn_update_dpp(0, __float_as_int(x), 0x4E, 0xF, 0xF, true);
  x += __int_as_float(t);
  t = __builtin_amdgcn_update_dpp(0, __float_as_int(x), 0x141, 0xF, 0xF, true);
  x += __int_as_float(t);
  return x;
}

// ---------------------------------------------------------------------------
// convX: split fp32 x[M,256] into bf16 hi/lo arrays (layer-0 GEMM input).
// ---------------------------------------------------------------------------
__global__ __launch_bounds__(256) void convX_kernel(
    const float* __restrict__ x, ushort* __restrict__ hiA,
    ushort* __restrict__ loA) {
  const int n4 = M_ * K_ / 4;
  for (int idx = blockIdx.x * blockDim.x + threadIdx.x; idx < n4;
       idx += gridDim.x * blockDim.x) {
    float4 v = ((const float4*)x)[idx];
    ushort4 h, l;
    h.x = f2bs(v.x); l.x = f2bs(v.x - bs2f(h.x));
    h.y = f2bs(v.y); l.y = f2bs(v.y - bs2f(h.y));
    h.z = f2bs(v.z); l.z = f2bs(v.z - bs2f(h.z));
    h.w = f2bs(v.w); l.w = f2bs(v.w - bs2f(h.w));
    ((ushort4*)hiA)[idx] = h;
    ((ushort4*)loA)[idx] = l;
  }
}

// ---------------------------------------------------------------------------
// convW: W[dir][256][384] fp32 -> W^T hi/lo bf16 [768 ncol][256 k].
// ---------------------------------------------------------------------------
__global__ __launch_bounds__(256) void convW_kernel(
    const float* __restrict__ W, ushort* __restrict__ WhiT,
    ushort* __restrict__ WloT) {
  const int ncol = blockIdx.x;           // 0..767
  const int dir = ncol / G_, j = ncol % G_;
  const int k = threadIdx.x;             // 0..255
  const float f = W[((size_t)dir * K_ + k) * G_ + j];
  const unsigned short hi = f2bs(f);
  WhiT[(size_t)ncol * K_ + k] = hi;
  WloT[(size_t)ncol * K_ + k] = f2bs(f - bs2f(hi));
}

// ---------------------------------------------------------------------------
// gemm3: C[M,768] = A[M,256] @ W^T' + bias, bf16 hi/lo 3-term split MFMA.
// ---------------------------------------------------------------------------
template <typename XT>
__global__ __launch_bounds__(256, 2) void gemm3_kernel(
    const ushort* __restrict__ Ahi, const ushort* __restrict__ Alo,
    const ushort* __restrict__ WhiT, const ushort* __restrict__ WloT,
    const float* __restrict__ bbias, XT* __restrict__ xp) {
  const int m0 = blockIdx.x * 128;
  const int n0 = blockIdx.y * 128;
  const int tid = threadIdx.x;
  const int w = tid >> 6, lane = tid & 63;
  const int wm = w >> 1, wn = w & 1;
  const int col = lane & 15, quad = lane >> 4;

  __shared__ __align__(16) ushort AH[128 * LDSROW];
  __shared__ __align__(16) ushort AL[128 * LDSROW];
  __shared__ __align__(16) ushort BH[128 * LDSROW];
  __shared__ __align__(16) ushort BL[128 * LDSROW];

  f32x4 acc[4][4];
#pragma unroll
  for (int i = 0; i < 4; ++i)
#pragma unroll
    for (int n = 0; n < 4; ++n) acc[i][n] = (f32x4){0.f, 0.f, 0.f, 0.f};

  const ushort* gsrc = (w == 0) ? Ahi : (w == 1) ? Alo : (w == 2) ? WhiT : WloT;
  ushort* lds = (w == 0) ? AH : (w == 1) ? AL : (w == 2) ? BH : BL;
  const int rbase = (w < 2) ? m0 : n0;

  for (int kb = 0; kb < K_; kb += 64) {
#pragma unroll
    for (int q = 0; q < 16; ++q) {
      const int slot = q * 64 + lane;
      const int r = slot >> 3, s = slot & 7;
      bf16x8 v = *(const bf16x8*)(gsrc + (size_t)(rbase + r) * K_ + kb + s * 8);
      *(bf16x8*)&lds[r * LDSROW + s * 8] = v;
    }
    __syncthreads();
#pragma unroll
    for (int z = 0; z < 2; ++z) {
      const int cc8 = (z * 4 + quad) * 8;
      bf16x8 ah[4], al[4], bh[4], bl[4];
#pragma unroll
      for (int i = 0; i < 4; ++i) {
        const int row = wm * 64 + i * 16 + col;
        ah[i] = *(const bf16x8*)&AH[row * LDSROW + cc8];
        al[i] = *(const bf16x8*)&AL[row * LDSROW + cc8];
      }
#pragma unroll
      for (int n = 0; n < 4; ++n) {
        const int row = wn * 64 + n * 16 + col;
        bh[n] = *(const bf16x8*)&BH[row * LDSROW + cc8];
        bl[n] = *(const bf16x8*)&BL[row * LDSROW + cc8];
      }
#pragma unroll
      for (int i = 0; i < 4; ++i)
#pragma unroll
        for (int n = 0; n < 4; ++n) {
          acc[i][n] = mfma16(ah[i], bh[n], acc[i][n]);
          acc[i][n] = mfma16(al[i], bh[n], acc[i][n]);
          acc[i][n] = mfma16(ah[i], bl[n], acc[i][n]);
        }
    }
    __syncthreads();
  }

  const int dir = (n0 >= G_) ? 1 : 0;
#pragma unroll
  for (int n = 0; n < 4; ++n) {
    const int ncol = n0 + wn * 64 + n * 16 + col;
    const int g = ncol - dir * G_;
    const float bv = bbias[dir * 2 * G_ + g];
#pragma unroll
    for (int i = 0; i < 4; ++i) {
      const int mb = m0 + wm * 64 + i * 16 + quad * 4;
#pragma unroll
      for (int r = 0; r < 4; ++r) {
        const int m = mb + r;
        const int bb = m >> 9;          // T_ = 512
        const int t = m & (T_ - 1);
        stor(xp + ((size_t)(dir * T_ + t) * B_ + bb) * G_ + g,
             acc[i][n][r] + bv);
      }
    }
  }
}

DEV float4 ldU4(const float* U, int col, int k0) {
  float4 v;
  v.x = U[(size_t)(k0 + 0) * G_ + col];
  v.y = U[(size_t)(k0 + 1) * G_ + col];
  v.z = U[(size_t)(k0 + 2) * G_ + col];
  v.w = U[(size_t)(k0 + 3) * G_ + col];
  return v;
}

// ---------------------------------------------------------------------------
// Recurrence (R6 structure). Grid (128, 2): 2 batch rows/block, 768 threads.
// Thread (cg=tid>>3, kc=tid&7) computes 4 columns [4cg,4cg+4) over k-chunk
// {32i+4kc..+4 : i<4}: 8 ds_read_b128, 64 v_pk_fma_f32, DPP 8-lane reduce.
// U: 32 NAMED f32x2 values, loaded by value, consumed directly by
// __builtin_elementwise_fma — no address-of, no pointer casts, no pin asm
// (R6's &u4 casts + pin were the suspected SROA spoiler that kept VGPR=68
// and demoted U to AGPR/L2 re-reads every step). launch_bounds(768,3) ->
// 168-VGPR cap; U(64) + working(~60) fits.
// ---------------------------------------------------------------------------
template <typename XT, bool LAST>
__global__ __launch_bounds__(768, 3) void rec_kernel(
    const XT* __restrict__ xp, const float* __restrict__ Ubase,
    const float* __restrict__ bbase, ushort* __restrict__ seqH,
    ushort* __restrict__ seqL, float* __restrict__ fin) {
  const int dir = blockIdx.y;
  const float* U = Ubase + dir * (H_ * G_);
  const float* bh = bbase + dir * (2 * G_) + G_;
  const int b0 = blockIdx.x * 2;
  const int tid = threadIdx.x;
  const int kc = tid & 7;        // k-chunk selector
  const int cg = tid >> 3;       // column group 0..95
  const int kc4 = kc * 4;

  __shared__ __align__(16) float hbuf[2][H_];
  __shared__ float rec_s[2][G_];

  // U fragments: col cg*4+c, k in [i*32+kc4, +4) -> pair a (k+0,1), b (k+2,3)
  f32x2 u00a, u00b, u01a, u01b, u02a, u02b, u03a, u03b;
  f32x2 u10a, u10b, u11a, u11b, u12a, u12b, u13a, u13b;
  f32x2 u20a, u20b, u21a, u21b, u22a, u22b, u23a, u23b;
  f32x2 u30a, u30b, u31a, u31b, u32a, u32b, u33a, u33b;
#define LDU2(c, i, va, vb)                                   \
  {                                                          \
    float4 t_ = ldU4(U, cg * 4 + (c), (i) * 32 + kc4);       \
    va = (f32x2){t_.x, t_.y};                                \
    vb = (f32x2){t_.z, t_.w};                                \
  }
  LDU2(0, 0, u00a, u00b) LDU2(0, 1, u01a, u01b)
  LDU2(0, 2, u02a, u02b) LDU2(0, 3, u03a, u03b)
  LDU2(1, 0, u10a, u10b) LDU2(1, 1, u11a, u11b)
  LDU2(1, 2, u12a, u12b) LDU2(1, 3, u13a, u13b)
  LDU2(2, 0, u20a, u20b) LDU2(2, 1, u21a, u21b)
  LDU2(2, 2, u22a, u22b) LDU2(2, 3, u23a, u23b)
  LDU2(3, 0, u30a, u30b) LDU2(3, 1, u31a, u31b)
  LDU2(3, 2, u32a, u32b) LDU2(3, 3, u33a, u33b)
#undef LDU2

  const int wc = kc & 3, wr = kc >> 2;     // this thread's rec_s write slot
  const float bmine = bh[cg * 4 + wc];

  const int grow = tid >> 7;        // gate-phase row (tid < 256)
  const int gu = tid & (H_ - 1);    // gate-phase unit
  const bool gateT = tid < 2 * H_;

  if (gateT) hbuf[grow][gu] = 0.f;

  const XT* xbase = xp + (size_t)(dir * T_) * B_ * G_;

  XT xzc{}, xrc{}, xhc{};
  {
    const int t0 = dir ? (T_ - 1) : 0;
    if (gateT) {
      const XT* xr_ = xbase + ((size_t)t0 * B_ + b0 + grow) * G_ + gu;
      xzc = xr_[0];
      xrc = xr_[H_];
      xhc = xr_[2 * H_];
    }
  }
  barrier_lds();

  for (int it = 0; it < T_; ++it) {
    const int t = dir ? (T_ - 1 - it) : it;

    // --- prefetch xp for step it+1 (hidden under the dot phase) ---
    XT xzn = xzc, xrn = xrc, xhn = xhc;
    if (gateT && (it + 1 < T_)) {
      const int tn = dir ? (t - 1) : (t + 1);
      const XT* xr_ = xbase + ((size_t)tn * B_ + b0 + grow) * G_ + gu;
      xzn = xr_[0];
      xrn = xr_[H_];
      xhn = xr_[2 * H_];
    }

    // --- dot phase: packed-fp32 FMA, 4 cols x 2 rows per thread ---
    f32x2 a00 = {0.f, 0.f}, a01 = {0.f, 0.f}, a02 = {0.f, 0.f}, a03 = {0.f, 0.f};
    f32x2 a10 = {0.f, 0.f}, a11 = {0.f, 0.f}, a12 = {0.f, 0.f}, a13 = {0.f, 0.f};
#define DOT_BLK(i, uAa, uAb, uBa, uBb, uCa, uCb, uDa, uDb)              \
  {                                                                     \
    float4 h0 = *(const float4*)&hbuf[0][(i) * 32 + kc4];               \
    float4 h1 = *(const float4*)&hbuf[1][(i) * 32 + kc4];               \
    f32x2 h0a = {h0.x, h0.y}, h0b = {h0.z, h0.w};                       \
    f32x2 h1a = {h1.x, h1.y}, h1b = {h1.z, h1.w};                       \
    a00 = __builtin_elementwise_fma(h0a, uAa, a00);                     \
    a00 = __builtin_elementwise_fma(h0b, uAb, a00);                     \
    a01 = __builtin_elementwise_fma(h0a, uBa, a01);                     \
    a01 = __builtin_elementwise_fma(h0b, uBb, a01);                     \
    a02 = __builtin_elementwise_fma(h0a, uCa, a02);                     \
    a02 = __builtin_elementwise_fma(h0b, uCb, a02);                     \
    a03 = __builtin_elementwise_fma(h0a, uDa, a03);                     \
    a03 = __builtin_elementwise_fma(h0b, uDb, a03);                     \
    a10 = __builtin_elementwise_fma(h1a, uAa, a10);                     \
    a10 = __builtin_elementwise_fma(h1b, uAb, a10);                     \
    a11 = __builtin_elementwise_fma(h1a, uBa, a11);                     \
    a11 = __builtin_elementwise_fma(h1b, uBb, a11);                     \
    a12 = __builtin_elementwise_fma(h1a, uCa, a12);                     \
    a12 = __builtin_elementwise_fma(h1b, uCb, a12);                     \
    a13 = __builtin_elementwise_fma(h1a, uDa, a13);                     \
    a13 = __builtin_elementwise_fma(h1b, uDb, a13);                     \
  }
    DOT_BLK(0, u00a, u00b, u10a, u10b, u20a, u20b, u30a, u30b)
    DOT_BLK(1, u01a, u01b, u11a, u11b, u21a, u21b, u31a, u31b)
    DOT_BLK(2, u02a, u02b, u12a, u12b, u22a, u22b, u32a, u32b)
    DOT_BLK(3, u03a, u03b, u13a, u13b, u23a, u23b, u33a, u33b)
#undef DOT_BLK

    float s00 = a00.x + a00.y, s01 = a01.x + a01.y;
    float s02 = a02.x + a02.y, s03 = a03.x + a03.y;
    float s10 = a10.x + a10.y, s11 = a11.x + a11.y;
    float s12 = a12.x + a12.y, s13 = a13.x + a13.y;
    s00 = dpp_red8(s00); s01 = dpp_red8(s01);
    s02 = dpp_red8(s02); s03 = dpp_red8(s03);
    s10 = dpp_red8(s10); s11 = dpp_red8(s11);
    s12 = dpp_red8(s12); s13 = dpp_red8(s13);

    const float va = wc == 0 ? s00 : wc == 1 ? s01 : wc == 2 ? s02 : s03;
    const float vb = wc == 0 ? s10 : wc == 1 ? s11 : wc == 2 ? s12 : s13;
    rec_s[wr][cg * 4 + wc] = (wr ? vb : va) + bmine;
    barrier_lds();

    // --- gate phase (first 256 threads) ---
    if (gateT) {
      const float xz = tof(xzc);
      const float xr = tof(xrc);
      const float xh = tof(xhc);
      const float rz = rec_s[grow][gu];
      const float rr = rec_s[grow][H_ + gu];
      const float rh = rec_s[grow][2 * H_ + gu];
      const float z = fsigmoid(xz + rz);
      const float r = fsigmoid(xr + rr);
      const float hh = ftanh(xh + r * rh);
      const float hold = hbuf[grow][gu];
      const float hn = z * hold + (1.f - z) * hh;
      hbuf[grow][gu] = hn;
      if constexpr (!LAST) {
        const size_t sidx =
            ((size_t)(b0 + grow) * T_ + t) * (2 * H_) + dir * H_ + gu;
        const unsigned short hi = f2bs(hn);
        seqH[sidx] = hi;
        seqL[sidx] = f2bs(hn - bs2f(hi));
      }
      xzc = xzn;
      xrc = xrn;
      xhc = xhn;
    }
    barrier_lds();
  }

  if constexpr (LAST) {
    if (gateT) fin[(size_t)(b0 + grow) * (2 * H_) + dir * H_ + gu] =
        hbuf[grow][gu];
  }
}

// ---------------------------------------------------------------------------
// Dense head: out[b] = sigmoid(fin[b][:] . Wd + bd)
// ---------------------------------------------------------------------------
__global__ void dense_kernel(const float* __restrict__ fin,
                             const float* __restrict__ Wd,
                             const float* __restrict__ bd,
                             float* __restrict__ out) {
  __shared__ float w[2 * H_];
  const int tid = threadIdx.x;
  w[tid] = Wd[tid];
  __syncthreads();
  float s = bd[0];
  const float* row = fin + tid * (2 * H_);
#pragma unroll 8
  for (int jj = 0; jj < 2 * H_; ++jj) s = fmaf(row[jj], w[jj], s);
  out[tid] = 1.f / (1.f + __expf(-s));
}

// ---------------------------------------------------------------------------
template <typename XT>
static void run_model(const float* x, const float* Ws, const float* Us,
                      const float* bs, const float* Wd, const float* bd,
                      float* out, char* ws, hipStream_t stream) {
  const size_t xpB = (size_t)2 * T_ * B_ * G_ * sizeof(XT);
  const size_t seqB = (size_t)B_ * T_ * 2 * H_ * 2;  // bf16 bits
  XT* xp = (XT*)ws;
  ushort* sHA = (ushort*)(ws + xpB);
  ushort* sLA = (ushort*)(ws + xpB + seqB);
  ushort* sHB = (ushort*)(ws + xpB + 2 * seqB);
  ushort* sLB = (ushort*)(ws + xpB + 3 * seqB);
  ushort* WhiT = (ushort*)(ws + xpB + 4 * seqB);
  ushort* WloT = WhiT + (size_t)768 * K_;
  float* fin = (float*)(ws + xpB + 4 * seqB + (size_t)2 * 768 * K_ * 2);

  convX_kernel<<<4096, 256, 0, stream>>>(x, sHB, sLB);

  const ushort* AHs[3] = {sHB, sHA, sHB};
  const ushort* ALs[3] = {sLB, sLA, sLB};
  ushort* oH[3] = {sHA, sHB, nullptr};
  ushort* oL[3] = {sLA, sLB, nullptr};

  for (int l = 0; l < 3; ++l) {
    const float* Wl = Ws + (size_t)l * 2 * K_ * G_;
    const float* bl = bs + (size_t)l * 4 * G_;
    const float* Ul = Us + (size_t)l * 2 * H_ * G_;
    convW_kernel<<<768, 256, 0, stream>>>(Wl, WhiT, WloT);
    gemm3_kernel<XT><<<dim3(M_ / 128, 6), 256, 0, stream>>>(
        AHs[l], ALs[l], WhiT, WloT, bl, xp);
    if (l < 2)
      rec_kernel<XT, false><<<dim3(B_ / 2, 2), 768, 0, stream>>>(
          xp, Ul, bl, oH[l], oL[l], nullptr);
    else
      rec_kernel<XT, true><<<dim3(B_ / 2, 2), 768, 0, stream>>>(
          xp, Ul, bl, nullptr, nullptr, fin);
  }
  dense_kernel<<<1, B_, 0, stream>>>(fin, Wd, bd, out);
}

extern "C" void kernel_launch(void* const* d_in, const int* in_sizes, int n_in,
                              void* d_out, int out_size, void* d_ws,
                              size_t ws_size, hipStream_t stream) {
  const float* x = (const float*)d_in[0];
  const float* Ws = (const float*)d_in[1];
  const float* Us = (const float*)d_in[2];
  const float* bs = (const float*)d_in[3];
  const float* Wd = (const float*)d_in[4];
  const float* bd = (const float*)d_in[5];
  float* out = (float*)d_out;
  char* ws = (char*)d_ws;

  const size_t seqB = (size_t)B_ * T_ * 2 * H_ * 2;
  const size_t wtB = (size_t)2 * 768 * K_ * 2;
  const size_t finB = (size_t)B_ * 2 * H_ * 4;
  const size_t xp32 = (size_t)2 * T_ * B_ * G_ * 4;
  const size_t tierA = xp32 + 4 * seqB + wtB + finB;      // ~641 MiB, fp32 xp
  if (ws_size >= tierA)
    run_model<float>(x, Ws, Us, bs, Wd, bd, out, ws, stream);
  else
    run_model<bf16>(x, Ws, Us, bs, Wd, bd, out, ws, stream);
}